// Round 3
// baseline (3785.369 us; speedup 1.0000x reference)
//
#include <hip/hip_runtime.h>
#include <hip/hip_bf16.h>
#include <math.h>

typedef __hip_bfloat16 bf16;
__device__ __forceinline__ float toF(float v){ return v; }
__device__ __forceinline__ float toF(bf16 v){ return __bfloat162float(v); }
__device__ __forceinline__ bf16 f2bf(float v){ return __float2bfloat16(v); }

#define D_    300
#define H_    5
#define NB    64
#define LL    1024
#define KK    64
#define ETXT  2048
#define EIMG  512
#define MAXDEG 128

// Mask storage modes: 0 = 4-byte word (int32/f32), 1 = 2-byte (bf16/f16),
// 2 = 1-byte (bool), 3 = 8-byte (int64/f64).
__device__ __forceinline__ int read_mask(const void* p, int i, int mode) {
  switch (mode) {
    case 1: return ((const unsigned short*)p)[i] != 0;
    case 2: return ((const unsigned char*)p)[i] != 0;
    case 3: { const unsigned int* w = (const unsigned int*)p;
              return (w[2*i] | w[2*i+1]) != 0; }
    default: return ((const unsigned int*)p)[i] != 0;
  }
}

// Detect mask element width from content of key_padding_mask (~10% ones).
__global__ void k_detect(const unsigned int* __restrict__ w, int nwords,
                         int* __restrict__ mode) {
  __shared__ unsigned int se[256], so[256];
  unsigned int oe = 0, oo = 0;
  for (int i = threadIdx.x; i < nwords; i += 256) {
    unsigned int v = w[i];
    if (i & 1) oo |= v; else oe |= v;
  }
  se[threadIdx.x] = oe; so[threadIdx.x] = oo;
  __syncthreads();
  for (int s = 128; s; s >>= 1) {
    if (threadIdx.x < s) { se[threadIdx.x] |= se[threadIdx.x+s]; so[threadIdx.x] |= so[threadIdx.x+s]; }
    __syncthreads();
  }
  if (threadIdx.x == 0) {
    unsigned int O = se[0] | so[0];
    int m = 0;
    if (O == 0u) m = 0;
    else if ((O & 0xFFFFu) == 0x3F80u) m = 1;                    // bf16 1.0 halfwords
    else if ((O >> 16) == 0x3F80u && (O & 0xFFFFu) == 0u) m = 0; // f32 1.0f words
    else if ((O >> 16) == 0x3FF0u) m = 3;                        // f64 1.0 high words
    else if (O <= 1u) m = (so[0] == 0u && se[0] != 0u) ? 3 : 0;  // int64 vs int32
    else if ((O & 0xFEFEFEFEu) == 0u) m = 2;                     // 0/1 bytes
    mode[0] = m;
  }
}

// ---------------- c[n,d] = sum_l score[n,l,d]*t2[n,l,d] ----------------
__global__ void k_c(const float* __restrict__ t2, const float* __restrict__ score,
                    float* __restrict__ c) {
  int n = blockIdx.x;
  int d = blockIdx.y * 128 + threadIdx.x;
  if (d >= D_) return;
  const float* tp = t2 + (size_t)n * LL * D_ + d;
  const float* sp = score + (size_t)n * LL * D_ + d;
  float acc = 0.f;
  for (int l = 0; l < LL; ++l)
    acc += tp[(size_t)l * D_] * sp[(size_t)l * D_];
  c[n * D_ + d] = acc;
}

__device__ __forceinline__ float clamp_logit(float v) {
  if (!(v > -1e30f)) v = -1e30f;   // catches NaN too
  if (v > 1e30f) v = 1e30f;
  return v;
}

// ---------------- pa_token logits (wave per row) ----------------
__global__ void k_logits_tok(const float* __restrict__ x, const float* __restrict__ w,
                             const float* __restrict__ b, const void* __restrict__ mask,
                             const int* __restrict__ mmode,
                             float* __restrict__ logits, int rows) {
  int row = blockIdx.x * blockDim.y + threadIdx.y;
  if (row >= rows) return;
  int lane = threadIdx.x;
  const float* xp = x + (size_t)row * D_;
  float acc = 0.f;
  for (int d = lane; d < D_; d += 64) acc += xp[d] * w[d];
#pragma unroll
  for (int off = 32; off; off >>= 1) acc += __shfl_down(acc, off);
  if (lane == 0) {
    float v = clamp_logit(acc + b[0]);
    if (read_mask(mask, row, mmode[0])) v = -INFINITY;
    logits[row] = v;
  }
}

// pa_np logits over (N, L+1): rows l<L from X (bf16), row L from c (f32)
__global__ void k_logits_np(const bf16* __restrict__ X, const float* __restrict__ c,
                            const float* __restrict__ w, const float* __restrict__ b,
                            const void* __restrict__ mask, const int* __restrict__ mmode,
                            float* __restrict__ logits) {
  int row = blockIdx.x * blockDim.y + threadIdx.y;
  if (row >= NB * (LL + 1)) return;
  int n = row / (LL + 1), l = row % (LL + 1);
  int lane = threadIdx.x;
  float acc = 0.f;
  if (l < LL) {
    const bf16* xp = X + ((size_t)n * LL + l) * D_;
    for (int d = lane; d < D_; d += 64) acc += toF(xp[d]) * w[d];
  } else {
    const float* cp = c + n * D_;
    for (int d = lane; d < D_; d += 64) acc += cp[d] * w[d];
  }
#pragma unroll
  for (int off = 32; off; off >>= 1) acc += __shfl_down(acc, off);
  if (lane == 0) {
    float v = clamp_logit(acc + b[0]);
    if (read_mask(mask, row, mmode[0])) v = -INFINITY;
    logits[row] = v;
  }
}

// ---------------- softmax over L + weighted sum of t2 rows -> u1[n,:] ----------------
__global__ __launch_bounds__(256) void k_soft_u1(const float* __restrict__ logits,
                                                 const float* __restrict__ t2,
                                                 float* __restrict__ u1) {
  int n = blockIdx.x, tid = threadIdx.x;
  __shared__ float w[LL];
  __shared__ float red[4];
  __shared__ float stat;
  float m = -INFINITY;
  for (int l = tid; l < LL; l += 256) { float v = logits[n * LL + l]; w[l] = v; m = fmaxf(m, v); }
#pragma unroll
  for (int off = 32; off; off >>= 1) m = fmaxf(m, __shfl_down(m, off));
  if ((tid & 63) == 0) red[tid >> 6] = m;
  __syncthreads();
  if (tid == 0) stat = fmaxf(fmaxf(red[0], red[1]), fmaxf(red[2], red[3]));
  __syncthreads();
  float M = stat;
  if (!(M > -INFINITY && M < INFINITY)) M = 0.f;
  float s = 0.f;
  for (int l = tid; l < LL; l += 256) { float p = __expf(w[l] - M); w[l] = p; s += p; }
#pragma unroll
  for (int off = 32; off; off >>= 1) s += __shfl_down(s, off);
  __syncthreads();
  if ((tid & 63) == 0) red[tid >> 6] = s;
  __syncthreads();
  if (tid == 0) stat = red[0] + red[1] + red[2] + red[3];
  __syncthreads();
  float inv = (stat > 0.f) ? 1.f / stat : 0.f;
  for (int d = tid; d < D_; d += 256) {
    float acc = 0.f;
    const float* tp = t2 + (size_t)n * LL * D_ + d;
    for (int l = 0; l < LL; ++l) acc += w[l] * tp[(size_t)l * D_];
    u1[n * D_ + d] = acc * inv;
  }
}

__global__ __launch_bounds__(256) void k_soft_u2(const float* __restrict__ logits,
                                                 const bf16* __restrict__ X,
                                                 const float* __restrict__ c,
                                                 float* __restrict__ u2) {
  int n = blockIdx.x, tid = threadIdx.x;
  __shared__ float w[LL + 1];
  __shared__ float red[4];
  __shared__ float stat;
  float m = -INFINITY;
  for (int l = tid; l < LL + 1; l += 256) { float v = logits[n * (LL + 1) + l]; w[l] = v; m = fmaxf(m, v); }
#pragma unroll
  for (int off = 32; off; off >>= 1) m = fmaxf(m, __shfl_down(m, off));
  if ((tid & 63) == 0) red[tid >> 6] = m;
  __syncthreads();
  if (tid == 0) stat = fmaxf(fmaxf(red[0], red[1]), fmaxf(red[2], red[3]));
  __syncthreads();
  float M = stat;
  if (!(M > -INFINITY && M < INFINITY)) M = 0.f;
  float s = 0.f;
  for (int l = tid; l < LL + 1; l += 256) { float p = __expf(w[l] - M); w[l] = p; s += p; }
#pragma unroll
  for (int off = 32; off; off >>= 1) s += __shfl_down(s, off);
  __syncthreads();
  if ((tid & 63) == 0) red[tid >> 6] = s;
  __syncthreads();
  if (tid == 0) stat = red[0] + red[1] + red[2] + red[3];
  __syncthreads();
  float inv = (stat > 0.f) ? 1.f / stat : 0.f;
  for (int d = tid; d < D_; d += 256) {
    float acc = 0.f;
    const bf16* xp = X + (size_t)n * LL * D_ + d;
    for (int l = 0; l < LL; ++l) acc += w[l] * toF(xp[(size_t)l * D_]);
    acc += w[LL] * c[n * D_ + d];
    u2[n * D_ + d] = acc * inv;
  }
}

// ---------------- wsrc[h,d] = sum_e W[d,h,e]*att_src[h,e] (and wdst) ----------------
__global__ void k_wvec(const float* __restrict__ W, const float* __restrict__ att_src,
                       const float* __restrict__ att_dst, float* __restrict__ wsrc,
                       float* __restrict__ wdst) {
  int idx = blockIdx.x * blockDim.x + threadIdx.x;
  if (idx >= 2 * H_ * D_) return;
  int s = idx / (H_ * D_);
  int r = idx % (H_ * D_);
  int h = r / D_, d = r % D_;
  const float* att = (s ? att_dst : att_src) + h * D_;
  const float* Wp = W + (size_t)d * H_ * D_ + h * D_;
  float acc = 0.f;
  for (int e = 0; e < D_; ++e) acc += Wp[e] * att[e];
  (s ? wdst : wsrc)[h * D_ + d] = acc;
}

// ---------------- a_src/a_dst[row,h] = x[row,:] . wvec[h,:] ----------------
template <typename T>
__global__ void k_asrc(const T* __restrict__ x, const float* __restrict__ wsrc,
                       const float* __restrict__ wdst, float* __restrict__ a_src,
                       float* __restrict__ a_dst, int rows) {
  int row = blockIdx.x * blockDim.y + threadIdx.y;
  if (row >= rows) return;
  int lane = threadIdx.x;
  const T* xp = x + (size_t)row * D_;
  float xr[5];
#pragma unroll
  for (int i = 0; i < 5; ++i) { int d = lane + 64 * i; xr[i] = (d < D_) ? toF(xp[d]) : 0.f; }
#pragma unroll
  for (int hh = 0; hh < H_; ++hh) {
    float as = 0.f, ad = 0.f;
#pragma unroll
    for (int i = 0; i < 5; ++i) {
      int d = lane + 64 * i;
      if (d < D_) { as += xr[i] * wsrc[hh * D_ + d]; ad += xr[i] * wdst[hh * D_ + d]; }
    }
#pragma unroll
    for (int off = 32; off; off >>= 1) { as += __shfl_down(as, off); ad += __shfl_down(ad, off); }
    if (lane == 0) { a_src[(size_t)row * H_ + hh] = as; a_dst[(size_t)row * H_ + hh] = ad; }
  }
}

// ---------------- GEMM: A(M x 300, T) @ B(300 x 1500, f32) -> C(M x 1500, bf16) ----------------
#define BM 64
#define BN 64
#define BK 60
template <typename T>
__global__ __launch_bounds__(256) void k_gemm(const T* __restrict__ A,
                                              const float* __restrict__ B,
                                              bf16* __restrict__ C, int M) {
  __shared__ float As[BK][BM];  // k-major
  __shared__ float Bs[BK][BN];
  int m0 = blockIdx.x * BM, n0 = blockIdx.y * BN;
  int tid = threadIdx.x;
  float acc[4][4] = {};
  int r0 = (tid >> 4) << 2;
  int c0 = (tid & 15) << 2;
  for (int k0 = 0; k0 < D_; k0 += BK) {
    for (int idx = tid; idx < BM * BK; idx += 256) {
      int m = idx / BK, k = idx % BK;
      As[k][m] = toF(A[(size_t)(m0 + m) * D_ + k0 + k]);
    }
    for (int idx = tid; idx < BK * BN; idx += 256) {
      int k = idx / BN, j = idx % BN;
      int col = n0 + j;
      Bs[k][j] = (col < H_ * D_) ? B[(size_t)(k0 + k) * (H_ * D_) + col] : 0.f;
    }
    __syncthreads();
    for (int kk = 0; kk < BK; ++kk) {
      float ra[4], rb[4];
#pragma unroll
      for (int i = 0; i < 4; ++i) ra[i] = As[kk][r0 + i];
#pragma unroll
      for (int j = 0; j < 4; ++j) rb[j] = Bs[kk][c0 + j];
#pragma unroll
      for (int i = 0; i < 4; ++i)
#pragma unroll
        for (int j = 0; j < 4; ++j) acc[i][j] += ra[i] * rb[j];
    }
    __syncthreads();
  }
  for (int i = 0; i < 4; ++i) {
    int m = m0 + r0 + i;
    for (int j = 0; j < 4; ++j) {
      int col = n0 + c0 + j;
      if (col < H_ * D_) C[(size_t)m * (H_ * D_) + col] = f2bf(acc[i][j]);
    }
  }
}

// ---------------- fused GAT aggregation + bias + relu + LayerNorm ----------------
// Reads only h/a_src/a_dst; writes xout -> may alias layer input (in-place safe).
__global__ __launch_bounds__(128) void k_agg_ln(
    const bf16* __restrict__ h, const float* __restrict__ a_src, const float* __restrict__ a_dst,
    const int* __restrict__ edges, int estride, int E, int nodes,
    const void* __restrict__ gmask, const int* __restrict__ mmode, int g_off,
    const float* __restrict__ bias, const float* __restrict__ g_ln, const float* __restrict__ b_ln,
    bf16* __restrict__ xout) {
  int g = blockIdx.x / nodes;
  int node = blockIdx.x % nodes;
  int tid = threadIdx.x;
  __shared__ int elist[MAXDEG];
  __shared__ int slist[MAXDEG];
  __shared__ float al[MAXDEG][H_];
  __shared__ int cnt;
  __shared__ float redA[2], redB[2];
  if (tid == 0) cnt = 0;
  __syncthreads();
  const int* src = edges + (size_t)(g_off + g) * estride;
  const int* dst = src + E;
  for (int e = tid; e < E; e += 128) {
    if (dst[e] == node) {
      int p = atomicAdd(&cnt, 1);
      if (p < MAXDEG) elist[p] = e;
    }
  }
  __syncthreads();
  int deg = cnt < MAXDEG ? cnt : MAXDEG;
  for (int i = tid; i < deg; i += 128) slist[i] = src[elist[i]];
  __syncthreads();
  const float* adr = a_dst + ((size_t)g * nodes + node) * H_;
  for (int i = tid; i < deg * H_; i += 128) {
    int ei = i / H_, hh = i - ei * H_;
    float v = a_src[((size_t)g * nodes + slist[ei]) * H_ + hh] + adr[hh];
    al[ei][hh] = v > 0.f ? v : 0.2f * v;
  }
  __syncthreads();
  if (tid < H_) {  // per-head softmax over incident edges
    float m = -INFINITY;
    for (int i = 0; i < deg; ++i) m = fmaxf(m, al[i][tid]);
    float s = 0.f;
    for (int i = 0; i < deg; ++i) { float p = __expf(al[i][tid] - m); al[i][tid] = p; s += p; }
    float inv = 1.f / (s + 1e-16f);
    for (int i = 0; i < deg; ++i) al[i][tid] *= inv;
  }
  __syncthreads();
  int msk = gmask ? read_mask(gmask, g_off + g, mmode[0]) : 0;
  float y[3];
  float ps = 0.f, pq = 0.f;
#pragma unroll
  for (int t = 0; t < 3; ++t) {
    int d = tid + t * 128;
    float acc = 0.f;
    if (d < D_) {
      for (int i = 0; i < deg; ++i) {
        const bf16* hr = h + (((size_t)g * nodes + slist[i]) * H_) * D_ + d;
#pragma unroll
        for (int hh = 0; hh < H_; ++hh) acc += al[i][hh] * toF(hr[(size_t)hh * D_]);
      }
      acc = acc * (1.f / H_) + bias[d];
      if (msk) acc = 0.f;
      acc = fmaxf(acc, 0.f);
      ps += acc; pq += acc * acc;
    }
    y[t] = acc;
  }
#pragma unroll
  for (int off = 32; off; off >>= 1) { ps += __shfl_down(ps, off); pq += __shfl_down(pq, off); }
  if ((tid & 63) == 0) { redA[tid >> 6] = ps; redB[tid >> 6] = pq; }
  __syncthreads();
  float mu = (redA[0] + redA[1]) * (1.f / 300.f);
  float var = (redB[0] + redB[1]) * (1.f / 300.f) - mu * mu;
  var = fmaxf(var, 0.f);
  float rstd = rsqrtf(var + 1e-5f);
#pragma unroll
  for (int t = 0; t < 3; ++t) {
    int d = tid + t * 128;
    if (d < D_) {
      float o = (y[t] - mu) * rstd * g_ln[d] + b_ln[d];
      xout[((size_t)g * nodes + node) * D_ + d] = f2bf(o);
    }
  }
}

// ---------------- final: out[n, k]=a1, out[n, K+k]=a2 (f32 out) ----------------
__global__ void k_out(const float* __restrict__ u1, const float* __restrict__ u2,
                      const float* __restrict__ v2, const bf16* __restrict__ v3,
                      float* __restrict__ out) {
  int idx = blockIdx.x * blockDim.y + threadIdx.y;
  if (idx >= NB * KK) return;
  int n = idx / KK, k = idx - n * KK;
  int lane = threadIdx.x;
  const float* ap = v2 + (size_t)idx * D_;
  const bf16* bp = v3 + (size_t)idx * D_;
  const float* u1p = u1 + n * D_;
  const float* u2p = u2 + n * D_;
  float a1 = 0.f, a2 = 0.f;
  for (int d = lane; d < D_; d += 64) { a1 += u1p[d] * ap[d]; a2 += u2p[d] * toF(bp[d]); }
#pragma unroll
  for (int off = 32; off; off >>= 1) { a1 += __shfl_down(a1, off); a2 += __shfl_down(a2, off); }
  if (lane == 0) {
    const float scale = 0.05773502691896258f;  // 1/sqrt(300)
    out[(size_t)n * 2 * KK + k] = a1 * scale;
    out[(size_t)n * 2 * KK + KK + k] = a2 * scale;
  }
}

extern "C" void kernel_launch(void* const* d_in, const int* in_sizes, int n_in,
                              void* d_out, int out_size, void* d_ws, size_t ws_size,
                              hipStream_t stream) {
  const float* t2    = (const float*)d_in[0];
  const float* v2    = (const float*)d_in[1];
  const float* score = (const float*)d_in[2];
  const int*   eidx  = (const int*)d_in[3];
  const void*  gmask = d_in[4];
  const void*  kpm   = d_in[5];
  const void*  npm   = d_in[6];
  const int*   iedge = (const int*)d_in[7];
  const float* txtW  = (const float*)d_in[8];
  const float* txtAs = (const float*)d_in[9];
  const float* txtAd = (const float*)d_in[10];
  const float* txtB  = (const float*)d_in[11];
  const float* imgW  = (const float*)d_in[12];
  const float* imgAs = (const float*)d_in[13];
  const float* imgAd = (const float*)d_in[14];
  const float* imgB  = (const float*)d_in[15];
  const float* w1    = (const float*)d_in[16];
  const float* b1    = (const float*)d_in[17];
  const float* w2    = (const float*)d_in[18];
  const float* b2    = (const float*)d_in[19];
  const float* lng   = (const float*)d_in[20];
  const float* lnb   = (const float*)d_in[21];
  float* out = (float*)d_out;

  char* ws = (char*)d_ws;
  size_t off = 0;
  auto alloc = [&](size_t bytes) -> char* {
    char* p = ws + off;
    off += (bytes + 511) & ~(size_t)511;
    return p;
  };
  int*   mmode = (int*)alloc(64);
  float* c    = (float*)alloc((size_t)NB * D_ * 4);
  float* u1   = (float*)alloc((size_t)NB * D_ * 4);
  float* u2   = (float*)alloc((size_t)NB * D_ * 4);
  float* lg1  = (float*)alloc((size_t)NB * LL * 4);
  float* lg2  = (float*)alloc((size_t)NB * (LL + 1) * 4);
  float* wsrc = (float*)alloc((size_t)H_ * D_ * 4);
  float* wdst = (float*)alloc((size_t)H_ * D_ * 4);
  float* asrc = (float*)alloc((size_t)NB * LL * H_ * 4);
  float* adst = (float*)alloc((size_t)NB * LL * H_ * 4);
  bf16* X = (bf16*)alloc((size_t)NB * LL * D_ * 2);   // txt state (in-place across layers)
  bf16* V = (bf16*)alloc((size_t)NB * KK * D_ * 2);   // img state (in-place across layers)
  size_t havail = (ws_size > off) ? (ws_size - off) : 0;
  bf16* hbuf = (bf16*)(ws + off);
  size_t per_g_txt = (size_t)LL * H_ * D_ * 2;
  int cg = (int)(havail / per_g_txt);
  if (cg < 1) cg = 1;
  if (cg > NB) cg = NB;
  size_t per_g_img = (size_t)KK * H_ * D_ * 2;
  int cgi = (int)(havail / per_g_img);
  if (cgi < 1) cgi = 1;
  if (cgi > NB) cgi = NB;

  dim3 b64x4(64, 4);

  // mask element-width detection from key_padding_mask content
  k_detect<<<1, 256, 0, stream>>>((const unsigned int*)kpm, NB * LL / 4, mmode);

  // phase 0: c, pa_token softmax -> u1
  k_c<<<dim3(NB, 3), 128, 0, stream>>>(t2, score, c);
  k_logits_tok<<<(NB * LL + 3) / 4, b64x4, 0, stream>>>(t2, w1, b1, kpm, mmode, lg1, NB * LL);
  k_soft_u1<<<NB, 256, 0, stream>>>(lg1, t2, u1);

  // text GAT (2 layers), chunked over graphs, in-place on X
  for (int layer = 0; layer < 2; ++layer) {
    const float* W = txtW + (size_t)layer * D_ * H_ * D_;
    k_wvec<<<(2 * H_ * D_ + 255) / 256, 256, 0, stream>>>(
        W, txtAs + layer * H_ * D_, txtAd + layer * H_ * D_, wsrc, wdst);
    for (int g0 = 0; g0 < NB; g0 += cg) {
      int gs = (cg < NB - g0) ? cg : (NB - g0);
      int M = gs * LL;
      bf16* Xout = X + (size_t)g0 * LL * D_;
      if (layer == 0) {
        const float* Xin = t2 + (size_t)g0 * LL * D_;
        k_asrc<float><<<(M + 3) / 4, b64x4, 0, stream>>>(Xin, wsrc, wdst, asrc, adst, M);
        k_gemm<float><<<dim3(M / 64, 24), 256, 0, stream>>>(Xin, W, hbuf, M);
      } else {
        const bf16* Xin = X + (size_t)g0 * LL * D_;
        k_asrc<bf16><<<(M + 3) / 4, b64x4, 0, stream>>>(Xin, wsrc, wdst, asrc, adst, M);
        k_gemm<bf16><<<dim3(M / 64, 24), 256, 0, stream>>>(Xin, W, hbuf, M);
      }
      k_agg_ln<<<M, 128, 0, stream>>>(hbuf, asrc, adst, eidx, 2 * ETXT, ETXT, LL,
                                      gmask, mmode, g0, txtB + layer * D_, lng, lnb, Xout);
    }
  }

  // image GAT (2 layers), shared edges, no gnn_mask, in-place on V
  for (int layer = 0; layer < 2; ++layer) {
    const float* W = imgW + (size_t)layer * D_ * H_ * D_;
    k_wvec<<<(2 * H_ * D_ + 255) / 256, 256, 0, stream>>>(
        W, imgAs + layer * H_ * D_, imgAd + layer * H_ * D_, wsrc, wdst);
    for (int g0 = 0; g0 < NB; g0 += cgi) {
      int gs = (cgi < NB - g0) ? cgi : (NB - g0);
      int M = gs * KK;
      bf16* Vout = V + (size_t)g0 * KK * D_;
      if (layer == 0) {
        const float* Vin = v2 + (size_t)g0 * KK * D_;
        k_asrc<float><<<(M + 3) / 4, b64x4, 0, stream>>>(Vin, wsrc, wdst, asrc, adst, M);
        k_gemm<float><<<dim3(M / 64, 24), 256, 0, stream>>>(Vin, W, hbuf, M);
      } else {
        const bf16* Vin = V + (size_t)g0 * KK * D_;
        k_asrc<bf16><<<(M + 3) / 4, b64x4, 0, stream>>>(Vin, wsrc, wdst, asrc, adst, M);
        k_gemm<bf16><<<dim3(M / 64, 24), 256, 0, stream>>>(Vin, W, hbuf, M);
      }
      k_agg_ln<<<M, 128, 0, stream>>>(hbuf, asrc, adst, iedge, 0, EIMG, KK,
                                      nullptr, mmode, 0, imgB + layer * D_, lng, lnb, Vout);
    }
  }

  // epilogue: pa_np softmax -> u2, then a1/a2
  k_logits_np<<<(NB * (LL + 1) + 3) / 4, b64x4, 0, stream>>>(X, c, w2, b2, npm, mmode, lg2);
  k_soft_u2<<<NB, 256, 0, stream>>>(lg2, X, c, u2);
  k_out<<<(NB * KK + 3) / 4, b64x4, 0, stream>>>(u1, u2, v2, V, out);
}

// Round 4
// 1397.982 us; speedup vs baseline: 2.7077x; 2.7077x over previous
//
#include <hip/hip_runtime.h>
#include <hip/hip_bf16.h>
#include <math.h>

typedef __hip_bfloat16 bf16;
__device__ __forceinline__ float toF(float v){ return v; }
__device__ __forceinline__ float toF(bf16 v){ return __bfloat162float(v); }
__device__ __forceinline__ bf16 f2bf(float v){ return __float2bfloat16(v); }

#define D_    300
#define H_    5
#define NB    64
#define LL    1024
#define KK    64
#define ETXT  2048
#define EIMG  512
#define MAXDEG 128
#define KP    320    // K padded (300 -> 320, 10 steps of 32)
#define NP    1536   // N padded (1500 -> 1536, 12 tiles of 128)

typedef __attribute__((ext_vector_type(8))) short short8;
typedef __attribute__((ext_vector_type(4))) float f32x4;

// Mask storage modes: 0 = 4-byte word (int32/f32), 1 = 2-byte, 2 = 1-byte (bool), 3 = 8-byte.
__device__ __forceinline__ int read_mask(const void* p, int i, int mode) {
  switch (mode) {
    case 1: return ((const unsigned short*)p)[i] != 0;
    case 2: return ((const unsigned char*)p)[i] != 0;
    case 3: { const unsigned int* w = (const unsigned int*)p;
              return (w[2*i] | w[2*i+1]) != 0; }
    default: return ((const unsigned int*)p)[i] != 0;
  }
}

__global__ void k_detect(const unsigned int* __restrict__ w, int nwords,
                         int* __restrict__ mode) {
  __shared__ unsigned int se[256], so[256];
  unsigned int oe = 0, oo = 0;
  for (int i = threadIdx.x; i < nwords; i += 256) {
    unsigned int v = w[i];
    if (i & 1) oo |= v; else oe |= v;
  }
  se[threadIdx.x] = oe; so[threadIdx.x] = oo;
  __syncthreads();
  for (int s = 128; s; s >>= 1) {
    if (threadIdx.x < s) { se[threadIdx.x] |= se[threadIdx.x+s]; so[threadIdx.x] |= so[threadIdx.x+s]; }
    __syncthreads();
  }
  if (threadIdx.x == 0) {
    unsigned int O = se[0] | so[0];
    int m = 0;
    if (O == 0u) m = 0;
    else if ((O & 0xFFFFu) == 0x3F80u) m = 1;
    else if ((O >> 16) == 0x3F80u && (O & 0xFFFFu) == 0u) m = 0;
    else if ((O >> 16) == 0x3FF0u) m = 3;
    else if (O <= 1u) m = (so[0] == 0u && se[0] != 0u) ? 3 : 0;
    else if ((O & 0xFEFEFEFEu) == 0u) m = 2;
    mode[0] = m;
  }
}

// ---------------- c[n,d] = sum_l score[n,l,d]*t2[n,l,d] ----------------
__global__ void k_c(const float* __restrict__ t2, const float* __restrict__ score,
                    float* __restrict__ c) {
  int n = blockIdx.x;
  int d = blockIdx.y * 128 + threadIdx.x;
  if (d >= D_) return;
  const float* tp = t2 + (size_t)n * LL * D_ + d;
  const float* sp = score + (size_t)n * LL * D_ + d;
  float acc = 0.f;
  for (int l = 0; l < LL; ++l)
    acc += tp[(size_t)l * D_] * sp[(size_t)l * D_];
  c[n * D_ + d] = acc;
}

__device__ __forceinline__ float clamp_logit(float v) {
  if (!(v > -1e30f)) v = -1e30f;
  if (v > 1e30f) v = 1e30f;
  return v;
}

// ---------------- pa_token logits (wave per row) ----------------
__global__ void k_logits_tok(const float* __restrict__ x, const float* __restrict__ w,
                             const float* __restrict__ b, const void* __restrict__ mask,
                             const int* __restrict__ mmode,
                             float* __restrict__ logits, int rows) {
  int row = blockIdx.x * blockDim.y + threadIdx.y;
  if (row >= rows) return;
  int lane = threadIdx.x;
  const float* xp = x + (size_t)row * D_;
  float acc = 0.f;
  for (int d = lane; d < D_; d += 64) acc += xp[d] * w[d];
#pragma unroll
  for (int off = 32; off; off >>= 1) acc += __shfl_down(acc, off);
  if (lane == 0) {
    float v = clamp_logit(acc + b[0]);
    if (read_mask(mask, row, mmode[0])) v = -INFINITY;
    logits[row] = v;
  }
}

// pa_np logits over (N, L+1): rows l<L from X (bf16), row L from c (f32)
__global__ void k_logits_np(const bf16* __restrict__ X, const float* __restrict__ c,
                            const float* __restrict__ w, const float* __restrict__ b,
                            const void* __restrict__ mask, const int* __restrict__ mmode,
                            float* __restrict__ logits) {
  int row = blockIdx.x * blockDim.y + threadIdx.y;
  if (row >= NB * (LL + 1)) return;
  int n = row / (LL + 1), l = row % (LL + 1);
  int lane = threadIdx.x;
  float acc = 0.f;
  if (l < LL) {
    const bf16* xp = X + ((size_t)n * LL + l) * D_;
    for (int d = lane; d < D_; d += 64) acc += toF(xp[d]) * w[d];
  } else {
    const float* cp = c + n * D_;
    for (int d = lane; d < D_; d += 64) acc += cp[d] * w[d];
  }
#pragma unroll
  for (int off = 32; off; off >>= 1) acc += __shfl_down(acc, off);
  if (lane == 0) {
    float v = clamp_logit(acc + b[0]);
    if (read_mask(mask, row, mmode[0])) v = -INFINITY;
    logits[row] = v;
  }
}

// ---------------- softmax over L + weighted sum of t2 rows -> u1[n,:] ----------------
__global__ __launch_bounds__(256) void k_soft_u1(const float* __restrict__ logits,
                                                 const float* __restrict__ t2,
                                                 float* __restrict__ u1) {
  int n = blockIdx.x, tid = threadIdx.x;
  __shared__ float w[LL];
  __shared__ float red[4];
  __shared__ float stat;
  float m = -INFINITY;
  for (int l = tid; l < LL; l += 256) { float v = logits[n * LL + l]; w[l] = v; m = fmaxf(m, v); }
#pragma unroll
  for (int off = 32; off; off >>= 1) m = fmaxf(m, __shfl_down(m, off));
  if ((tid & 63) == 0) red[tid >> 6] = m;
  __syncthreads();
  if (tid == 0) stat = fmaxf(fmaxf(red[0], red[1]), fmaxf(red[2], red[3]));
  __syncthreads();
  float M = stat;
  if (!(M > -INFINITY && M < INFINITY)) M = 0.f;
  float s = 0.f;
  for (int l = tid; l < LL; l += 256) { float p = __expf(w[l] - M); w[l] = p; s += p; }
#pragma unroll
  for (int off = 32; off; off >>= 1) s += __shfl_down(s, off);
  __syncthreads();
  if ((tid & 63) == 0) red[tid >> 6] = s;
  __syncthreads();
  if (tid == 0) stat = red[0] + red[1] + red[2] + red[3];
  __syncthreads();
  float inv = (stat > 0.f) ? 1.f / stat : 0.f;
  for (int d = tid; d < D_; d += 256) {
    float acc = 0.f;
    const float* tp = t2 + (size_t)n * LL * D_ + d;
    for (int l = 0; l < LL; ++l) acc += w[l] * tp[(size_t)l * D_];
    u1[n * D_ + d] = acc * inv;
  }
}

__global__ __launch_bounds__(256) void k_soft_u2(const float* __restrict__ logits,
                                                 const bf16* __restrict__ X,
                                                 const float* __restrict__ c,
                                                 float* __restrict__ u2) {
  int n = blockIdx.x, tid = threadIdx.x;
  __shared__ float w[LL + 1];
  __shared__ float red[4];
  __shared__ float stat;
  float m = -INFINITY;
  for (int l = tid; l < LL + 1; l += 256) { float v = logits[n * (LL + 1) + l]; w[l] = v; m = fmaxf(m, v); }
#pragma unroll
  for (int off = 32; off; off >>= 1) m = fmaxf(m, __shfl_down(m, off));
  if ((tid & 63) == 0) red[tid >> 6] = m;
  __syncthreads();
  if (tid == 0) stat = fmaxf(fmaxf(red[0], red[1]), fmaxf(red[2], red[3]));
  __syncthreads();
  float M = stat;
  if (!(M > -INFINITY && M < INFINITY)) M = 0.f;
  float s = 0.f;
  for (int l = tid; l < LL + 1; l += 256) { float p = __expf(w[l] - M); w[l] = p; s += p; }
#pragma unroll
  for (int off = 32; off; off >>= 1) s += __shfl_down(s, off);
  __syncthreads();
  if ((tid & 63) == 0) red[tid >> 6] = s;
  __syncthreads();
  if (tid == 0) stat = red[0] + red[1] + red[2] + red[3];
  __syncthreads();
  float inv = (stat > 0.f) ? 1.f / stat : 0.f;
  for (int d = tid; d < D_; d += 256) {
    float acc = 0.f;
    const bf16* xp = X + (size_t)n * LL * D_ + d;
    for (int l = 0; l < LL; ++l) acc += w[l] * toF(xp[(size_t)l * D_]);
    acc += w[LL] * c[n * D_ + d];
    u2[n * D_ + d] = acc * inv;
  }
}

// ---------------- wsrc[h,d] = sum_e W[d,h,e]*att_src[h,e] (and wdst) ----------------
__global__ void k_wvec(const float* __restrict__ W, const float* __restrict__ att_src,
                       const float* __restrict__ att_dst, float* __restrict__ wsrc,
                       float* __restrict__ wdst) {
  int idx = blockIdx.x * blockDim.x + threadIdx.x;
  if (idx >= 2 * H_ * D_) return;
  int s = idx / (H_ * D_);
  int r = idx % (H_ * D_);
  int h = r / D_, d = r % D_;
  const float* att = (s ? att_dst : att_src) + h * D_;
  const float* Wp = W + (size_t)d * H_ * D_ + h * D_;
  float acc = 0.f;
  for (int e = 0; e < D_; ++e) acc += Wp[e] * att[e];
  (s ? wdst : wsrc)[h * D_ + d] = acc;
}

// ---------------- a_src/a_dst[row,h] = x[row,:] . wvec[h,:] ----------------
template <typename T>
__global__ void k_asrc(const T* __restrict__ x, const float* __restrict__ wsrc,
                       const float* __restrict__ wdst, float* __restrict__ a_src,
                       float* __restrict__ a_dst, int rows) {
  int row = blockIdx.x * blockDim.y + threadIdx.y;
  if (row >= rows) return;
  int lane = threadIdx.x;
  const T* xp = x + (size_t)row * D_;
  float xr[5];
#pragma unroll
  for (int i = 0; i < 5; ++i) { int d = lane + 64 * i; xr[i] = (d < D_) ? toF(xp[d]) : 0.f; }
#pragma unroll
  for (int hh = 0; hh < H_; ++hh) {
    float as = 0.f, ad = 0.f;
#pragma unroll
    for (int i = 0; i < 5; ++i) {
      int d = lane + 64 * i;
      if (d < D_) { as += xr[i] * wsrc[hh * D_ + d]; ad += xr[i] * wdst[hh * D_ + d]; }
    }
#pragma unroll
    for (int off = 32; off; off >>= 1) { as += __shfl_down(as, off); ad += __shfl_down(ad, off); }
    if (lane == 0) { a_src[(size_t)row * H_ + hh] = as; a_dst[(size_t)row * H_ + hh] = ad; }
  }
}

// ---------------- pack A: (M x 300, T) -> (M x KP, bf16, zero-padded) ----------------
template <typename T>
__global__ void k_packA(const T* __restrict__ src, bf16* __restrict__ Ap, int M) {
  int idx = blockIdx.x * 256 + threadIdx.x;
  if (idx >= M * KP) return;
  int m = idx / KP, k = idx - m * KP;
  Ap[idx] = (k < D_) ? f2bf(toF(src[(size_t)m * D_ + k])) : f2bf(0.f);
}

// ---------------- pack B: (300 x 1500, f32) -> transposed (NP x KP, bf16, zero-pad) ----------------
__global__ void k_packB(const float* __restrict__ B, bf16* __restrict__ Bp) {
  int idx = blockIdx.x * 256 + threadIdx.x;
  if (idx >= NP * KP) return;
  int j = idx / KP, k = idx - j * KP;
  float v = (k < D_ && j < H_ * D_) ? B[(size_t)k * (H_ * D_) + j] : 0.f;
  Bp[idx] = f2bf(v);
}

// ---------------- MFMA GEMM: Ap(M x KP) @ Bp^T(NP x KP) -> C(M x NP, bf16) ----------------
__global__ __launch_bounds__(256) void k_gemm_mfma(const bf16* __restrict__ Ap,
                                                   const bf16* __restrict__ Bp,
                                                   bf16* __restrict__ C, int M) {
  __shared__ short As[128][40];   // rows m, k contiguous; +8 pad -> bank stride 20
  __shared__ short Bs[128][40];   // rows n, k contiguous
  int m0 = blockIdx.x * 128, n0 = blockIdx.y * 128;
  int tid = threadIdx.x;
  int wave = tid >> 6, lane = tid & 63;
  int wr = (wave >> 1) * 64, wc = (wave & 1) * 64;
  f32x4 acc[4][4] = {};
  for (int k0 = 0; k0 < KP; k0 += 32) {
    // stage A tile: 128 rows x 32 k = 512 x 16B chunks
#pragma unroll
    for (int cc = 0; cc < 2; ++cc) {
      int c = tid + cc * 256;
      int m = c >> 2, ko = (c & 3) << 3;
      int row = m0 + m; if (row >= M) row = M - 1;
      *(uint4*)&As[m][ko] = *(const uint4*)(Ap + (size_t)row * KP + k0 + ko);
    }
#pragma unroll
    for (int cc = 0; cc < 2; ++cc) {
      int c = tid + cc * 256;
      int n = c >> 2, ko = (c & 3) << 3;
      *(uint4*)&Bs[n][ko] = *(const uint4*)(Bp + (size_t)(n0 + n) * KP + k0 + ko);
    }
    __syncthreads();
    int kq = (lane >> 4) << 3;
    short8 af[4], bfr[4];
#pragma unroll
    for (int i = 0; i < 4; ++i) af[i]  = *(const short8*)&As[wr + i * 16 + (lane & 15)][kq];
#pragma unroll
    for (int j = 0; j < 4; ++j) bfr[j] = *(const short8*)&Bs[wc + j * 16 + (lane & 15)][kq];
#pragma unroll
    for (int i = 0; i < 4; ++i)
#pragma unroll
      for (int j = 0; j < 4; ++j)
        acc[i][j] = __builtin_amdgcn_mfma_f32_16x16x32_bf16(af[i], bfr[j], acc[i][j], 0, 0, 0);
    __syncthreads();
  }
  // epilogue: C/D layout col=lane&15, row=(lane>>4)*4+r
  int cl = lane & 15, rq = (lane >> 4) << 2;
#pragma unroll
  for (int i = 0; i < 4; ++i) {
#pragma unroll
    for (int j = 0; j < 4; ++j) {
      int col = n0 + wc + j * 16 + cl;
#pragma unroll
      for (int r = 0; r < 4; ++r) {
        int row = m0 + wr + i * 16 + rq + r;
        if (row < M) C[(size_t)row * NP + col] = f2bf(acc[i][j][r]);
      }
    }
  }
}

// ---------------- fused GAT aggregation + bias + relu + LayerNorm ----------------
// h rows have stride NP; head hh at column hh*D_. In-place safe w.r.t. layer input.
__global__ __launch_bounds__(128) void k_agg_ln(
    const bf16* __restrict__ h, const float* __restrict__ a_src, const float* __restrict__ a_dst,
    const int* __restrict__ edges, int estride, int E, int nodes,
    const void* __restrict__ gmask, const int* __restrict__ mmode, int g_off,
    const float* __restrict__ bias, const float* __restrict__ g_ln, const float* __restrict__ b_ln,
    bf16* __restrict__ xout) {
  int g = blockIdx.x / nodes;
  int node = blockIdx.x % nodes;
  int tid = threadIdx.x;
  __shared__ int elist[MAXDEG];
  __shared__ int slist[MAXDEG];
  __shared__ float al[MAXDEG][H_];
  __shared__ int cnt;
  __shared__ float redA[2], redB[2];
  if (tid == 0) cnt = 0;
  __syncthreads();
  const int* src = edges + (size_t)(g_off + g) * estride;
  const int* dst = src + E;
  for (int e = tid; e < E; e += 128) {
    if (dst[e] == node) {
      int p = atomicAdd(&cnt, 1);
      if (p < MAXDEG) elist[p] = e;
    }
  }
  __syncthreads();
  int deg = cnt < MAXDEG ? cnt : MAXDEG;
  for (int i = tid; i < deg; i += 128) slist[i] = src[elist[i]];
  __syncthreads();
  const float* adr = a_dst + ((size_t)g * nodes + node) * H_;
  for (int i = tid; i < deg * H_; i += 128) {
    int ei = i / H_, hh = i - ei * H_;
    float v = a_src[((size_t)g * nodes + slist[ei]) * H_ + hh] + adr[hh];
    al[ei][hh] = v > 0.f ? v : 0.2f * v;
  }
  __syncthreads();
  if (tid < H_) {
    float m = -INFINITY;
    for (int i = 0; i < deg; ++i) m = fmaxf(m, al[i][tid]);
    float s = 0.f;
    for (int i = 0; i < deg; ++i) { float p = __expf(al[i][tid] - m); al[i][tid] = p; s += p; }
    float inv = 1.f / (s + 1e-16f);
    for (int i = 0; i < deg; ++i) al[i][tid] *= inv;
  }
  __syncthreads();
  int msk = gmask ? read_mask(gmask, g_off + g, mmode[0]) : 0;
  float y[3];
  float ps = 0.f, pq = 0.f;
#pragma unroll
  for (int t = 0; t < 3; ++t) {
    int d = tid + t * 128;
    float acc = 0.f;
    if (d < D_) {
      for (int i = 0; i < deg; ++i) {
        const bf16* hr = h + (size_t)(g * nodes + slist[i]) * NP + d;
#pragma unroll
        for (int hh = 0; hh < H_; ++hh) acc += al[i][hh] * toF(hr[hh * D_]);
      }
      acc = acc * (1.f / H_) + bias[d];
      if (msk) acc = 0.f;
      acc = fmaxf(acc, 0.f);
      ps += acc; pq += acc * acc;
    }
    y[t] = acc;
  }
#pragma unroll
  for (int off = 32; off; off >>= 1) { ps += __shfl_down(ps, off); pq += __shfl_down(pq, off); }
  if ((tid & 63) == 0) { redA[tid >> 6] = ps; redB[tid >> 6] = pq; }
  __syncthreads();
  float mu = (redA[0] + redA[1]) * (1.f / 300.f);
  float var = (redB[0] + redB[1]) * (1.f / 300.f) - mu * mu;
  var = fmaxf(var, 0.f);
  float rstd = rsqrtf(var + 1e-5f);
#pragma unroll
  for (int t = 0; t < 3; ++t) {
    int d = tid + t * 128;
    if (d < D_) {
      float o = (y[t] - mu) * rstd * g_ln[d] + b_ln[d];
      xout[((size_t)g * nodes + node) * D_ + d] = f2bf(o);
    }
  }
}

// ---------------- final: out[n, k]=a1, out[n, K+k]=a2 (f32 out) ----------------
__global__ void k_out(const float* __restrict__ u1, const float* __restrict__ u2,
                      const float* __restrict__ v2, const bf16* __restrict__ v3,
                      float* __restrict__ out) {
  int idx = blockIdx.x * blockDim.y + threadIdx.y;
  if (idx >= NB * KK) return;
  int n = idx / KK, k = idx - n * KK;
  int lane = threadIdx.x;
  const float* ap = v2 + (size_t)idx * D_;
  const bf16* bp = v3 + (size_t)idx * D_;
  const float* u1p = u1 + n * D_;
  const float* u2p = u2 + n * D_;
  float a1 = 0.f, a2 = 0.f;
  for (int d = lane; d < D_; d += 64) { a1 += u1p[d] * ap[d]; a2 += u2p[d] * toF(bp[d]); }
#pragma unroll
  for (int off = 32; off; off >>= 1) { a1 += __shfl_down(a1, off); a2 += __shfl_down(a2, off); }
  if (lane == 0) {
    const float scale = 0.05773502691896258f;  // 1/sqrt(300)
    out[(size_t)n * 2 * KK + k] = a1 * scale;
    out[(size_t)n * 2 * KK + KK + k] = a2 * scale;
  }
}

extern "C" void kernel_launch(void* const* d_in, const int* in_sizes, int n_in,
                              void* d_out, int out_size, void* d_ws, size_t ws_size,
                              hipStream_t stream) {
  const float* t2    = (const float*)d_in[0];
  const float* v2    = (const float*)d_in[1];
  const float* score = (const float*)d_in[2];
  const int*   eidx  = (const int*)d_in[3];
  const void*  gmask = d_in[4];
  const void*  kpm   = d_in[5];
  const void*  npm   = d_in[6];
  const int*   iedge = (const int*)d_in[7];
  const float* txtW  = (const float*)d_in[8];
  const float* txtAs = (const float*)d_in[9];
  const float* txtAd = (const float*)d_in[10];
  const float* txtB  = (const float*)d_in[11];
  const float* imgW  = (const float*)d_in[12];
  const float* imgAs = (const float*)d_in[13];
  const float* imgAd = (const float*)d_in[14];
  const float* imgB  = (const float*)d_in[15];
  const float* w1    = (const float*)d_in[16];
  const float* b1    = (const float*)d_in[17];
  const float* w2    = (const float*)d_in[18];
  const float* b2    = (const float*)d_in[19];
  const float* lng   = (const float*)d_in[20];
  const float* lnb   = (const float*)d_in[21];
  float* out = (float*)d_out;

  char* ws = (char*)d_ws;
  size_t off = 0;
  auto alloc = [&](size_t bytes) -> char* {
    char* p = ws + off;
    off += (bytes + 511) & ~(size_t)511;
    return p;
  };
  int*   mmode = (int*)alloc(64);
  float* c    = (float*)alloc((size_t)NB * D_ * 4);
  float* u1   = (float*)alloc((size_t)NB * D_ * 4);
  float* u2   = (float*)alloc((size_t)NB * D_ * 4);
  float* lg1  = (float*)alloc((size_t)NB * LL * 4);
  float* lg2  = (float*)alloc((size_t)NB * (LL + 1) * 4);
  float* wsrc = (float*)alloc((size_t)H_ * D_ * 4);
  float* wdst = (float*)alloc((size_t)H_ * D_ * 4);
  float* asrc = (float*)alloc((size_t)NB * LL * H_ * 4);
  float* adst = (float*)alloc((size_t)NB * LL * H_ * 4);
  bf16* X  = (bf16*)alloc((size_t)NB * LL * D_ * 2);   // txt state (in-place across layers)
  bf16* V  = (bf16*)alloc((size_t)NB * KK * D_ * 2);   // img state (in-place across layers)
  bf16* Bp = (bf16*)alloc((size_t)NP * KP * 2);        // packed/transposed weights
  size_t havail = (ws_size > off) ? (ws_size - off) : 0;
  char* hstart = ws + off;
  // per-graph: Ap (rows x KP bf16) + hbuf (rows x NP bf16)
  size_t per_g_txt = (size_t)LL * (KP + NP) * 2;
  int cg = (int)(havail / per_g_txt);
  if (cg < 1) cg = 1;
  if (cg > NB) cg = NB;
  size_t per_g_img = (size_t)KK * (KP + NP) * 2;
  int cgi = (int)(havail / per_g_img);
  if (cgi < 1) cgi = 1;
  if (cgi > NB) cgi = NB;

  dim3 b64x4(64, 4);

  k_detect<<<1, 256, 0, stream>>>((const unsigned int*)kpm, NB * LL / 4, mmode);

  // phase 0: c, pa_token softmax -> u1
  k_c<<<dim3(NB, 3), 128, 0, stream>>>(t2, score, c);
  k_logits_tok<<<(NB * LL + 3) / 4, b64x4, 0, stream>>>(t2, w1, b1, kpm, mmode, lg1, NB * LL);
  k_soft_u1<<<NB, 256, 0, stream>>>(lg1, t2, u1);

  // text GAT (2 layers), chunked over graphs, in-place on X
  {
    bf16* Ap   = (bf16*)hstart;
    bf16* hbuf = (bf16*)(hstart + (size_t)cg * LL * KP * 2);
    for (int layer = 0; layer < 2; ++layer) {
      const float* W = txtW + (size_t)layer * D_ * H_ * D_;
      k_packB<<<(NP * KP + 255) / 256, 256, 0, stream>>>(W, Bp);
      k_wvec<<<(2 * H_ * D_ + 255) / 256, 256, 0, stream>>>(
          W, txtAs + layer * H_ * D_, txtAd + layer * H_ * D_, wsrc, wdst);
      for (int g0 = 0; g0 < NB; g0 += cg) {
        int gs = (cg < NB - g0) ? cg : (NB - g0);
        int M = gs * LL;
        bf16* Xout = X + (size_t)g0 * LL * D_;
        if (layer == 0) {
          const float* Xin = t2 + (size_t)g0 * LL * D_;
          k_packA<float><<<(M * KP + 255) / 256, 256, 0, stream>>>(Xin, Ap, M);
          k_asrc<float><<<(M + 3) / 4, b64x4, 0, stream>>>(Xin, wsrc, wdst, asrc, adst, M);
        } else {
          const bf16* Xin = X + (size_t)g0 * LL * D_;
          k_packA<bf16><<<(M * KP + 255) / 256, 256, 0, stream>>>(Xin, Ap, M);
          k_asrc<bf16><<<(M + 3) / 4, b64x4, 0, stream>>>(Xin, wsrc, wdst, asrc, adst, M);
        }
        k_gemm_mfma<<<dim3((M + 127) / 128, NP / 128), 256, 0, stream>>>(Ap, Bp, hbuf, M);
        k_agg_ln<<<M, 128, 0, stream>>>(hbuf, asrc, adst, eidx, 2 * ETXT, ETXT, LL,
                                        gmask, mmode, g0, txtB + layer * D_, lng, lnb, Xout);
      }
    }
  }

  // image GAT (2 layers), shared edges, no gnn_mask, in-place on V
  {
    bf16* Ap   = (bf16*)hstart;
    bf16* hbuf = (bf16*)(hstart + (size_t)cgi * KK * KP * 2);
    for (int layer = 0; layer < 2; ++layer) {
      const float* W = imgW + (size_t)layer * D_ * H_ * D_;
      k_packB<<<(NP * KP + 255) / 256, 256, 0, stream>>>(W, Bp);
      k_wvec<<<(2 * H_ * D_ + 255) / 256, 256, 0, stream>>>(
          W, imgAs + layer * H_ * D_, imgAd + layer * H_ * D_, wsrc, wdst);
      for (int g0 = 0; g0 < NB; g0 += cgi) {
        int gs = (cgi < NB - g0) ? cgi : (NB - g0);
        int M = gs * KK;
        bf16* Vout = V + (size_t)g0 * KK * D_;
        if (layer == 0) {
          const float* Vin = v2 + (size_t)g0 * KK * D_;
          k_packA<float><<<(M * KP + 255) / 256, 256, 0, stream>>>(Vin, Ap, M);
          k_asrc<float><<<(M + 3) / 4, b64x4, 0, stream>>>(Vin, wsrc, wdst, asrc, adst, M);
        } else {
          const bf16* Vin = V + (size_t)g0 * KK * D_;
          k_packA<bf16><<<(M * KP + 255) / 256, 256, 0, stream>>>(Vin, Ap, M);
          k_asrc<bf16><<<(M + 3) / 4, b64x4, 0, stream>>>(Vin, wsrc, wdst, asrc, adst, M);
        }
        k_gemm_mfma<<<dim3((M + 127) / 128, NP / 128), 256, 0, stream>>>(Ap, Bp, hbuf, M);
        k_agg_ln<<<M, 128, 0, stream>>>(hbuf, asrc, adst, iedge, 0, EIMG, KK,
                                        nullptr, mmode, 0, imgB + layer * D_, lng, lnb, Vout);
      }
    }
  }

  // epilogue: pa_np softmax -> u2, then a1/a2
  k_logits_np<<<(NB * (LL + 1) + 3) / 4, b64x4, 0, stream>>>(X, c, w2, b2, npm, mmode, lg2);
  k_soft_u2<<<NB, 256, 0, stream>>>(lg2, X, c, u2);
  k_out<<<(NB * KK + 3) / 4, b64x4, 0, stream>>>(u1, u2, v2, V, out);
}